// Round 1
// baseline (5779.462 us; speedup 1.0000x reference)
//
#include <hip/hip_runtime.h>

#define N_NODES 50000
#define N_EDGES 800000
#define D 64
#define NUM_LAYERS 4
#define NUM_GRAPHS 128

// ---------------- copy (agg init: h = x, since EPS == 0) ----------------
__global__ void copy_f4(const float4* __restrict__ in, float4* __restrict__ out, int n4) {
    int i = blockIdx.x * blockDim.x + threadIdx.x;
    if (i < n4) out[i] = in[i];
}

// ---------------- edge scatter: out[dst] += x[src] ----------------
// 16 threads per edge, each handles 4 contiguous floats (float4 load, 4 atomics).
__global__ void scatter_add(const float* __restrict__ x, float* __restrict__ out,
                            const int* __restrict__ src, const int* __restrict__ dst) {
    int tid = blockIdx.x * blockDim.x + threadIdx.x;   // exactly N_EDGES*16 threads
    int e = tid >> 4;
    int g = tid & 15;
    int s = src[e];
    int d = dst[e];
    float4 v = *((const float4*)(x + (size_t)s * D) + g);
    float* op = out + (size_t)d * D + g * 4;
    atomicAdd(op + 0, v.x);
    atomicAdd(op + 1, v.y);
    atomicAdd(op + 2, v.z);
    atomicAdd(op + 3, v.w);
}

// ---------------- y = relu(h @ W^T + b) ----------------
// out[n,o] = b[o] + sum_k h[n,k] * W[o*64+k].  4 nodes per 256-thread block.
// W staged in LDS with stride 65 (2-way bank aliasing = free; 64 would be 64-way).
__global__ __launch_bounds__(256) void linear_relu(const float* __restrict__ h,
                                                   float* __restrict__ y,
                                                   const float* __restrict__ W,
                                                   const float* __restrict__ b) {
    __shared__ float Wl[64 * 65];
    __shared__ float hl[4 * 64];
    int tid = threadIdx.x;
#pragma unroll
    for (int i = 0; i < 16; ++i) {
        int idx = i * 256 + tid;          // coalesced global read of W
        Wl[(idx >> 6) * 65 + (idx & 63)] = W[idx];
    }
    int node0 = blockIdx.x * 4;
    hl[tid] = h[(size_t)node0 * D + tid]; // 256 contiguous floats = 4 rows
    __syncthreads();
    int o  = tid & 63;
    int nl = tid >> 6;
    float acc = b[o];
#pragma unroll
    for (int k = 0; k < 64; ++k)
        acc += hl[nl * 64 + k] * Wl[o * 65 + k];   // hl: broadcast; Wl: 2-way (free)
    acc = fmaxf(acc, 0.0f);
    y[(size_t)(node0 + nl) * D + o] = acc;
}

// ---------------- pooled[batch[n]] += x[n] ----------------
__global__ void pool_kernel(const float* __restrict__ x, const int* __restrict__ batch,
                            float* __restrict__ out) {
    int tid = blockIdx.x * blockDim.x + threadIdx.x;   // exactly N_NODES*16
    int n = tid >> 4;
    int g = tid & 15;
    int gid = batch[n];
    float4 v = *((const float4*)(x + (size_t)n * D) + g);
    float* op = out + (size_t)gid * D + g * 4;
    atomicAdd(op + 0, v.x);
    atomicAdd(op + 1, v.y);
    atomicAdd(op + 2, v.z);
    atomicAdd(op + 3, v.w);
}

extern "C" void kernel_launch(void* const* d_in, const int* in_sizes, int n_in,
                              void* d_out, int out_size, void* d_ws, size_t ws_size,
                              hipStream_t stream) {
    const float* x_in  = (const float*)d_in[0];          // [50000, 64]
    const int*   ei    = (const int*)d_in[1];            // [2, 800000]
    const int*   eei   = (const int*)d_in[2];            // [2, 800000]
    const int*   batch = (const int*)d_in[3];            // [50000]
    const float* Ws    = (const float*)d_in[4];          // [4, 64, 64]
    const float* bs    = (const float*)d_in[5];          // [4, 64]
    float* out = (float*)d_out;                          // [128*64]

    float* A = (float*)d_ws;
    float* B = A + (size_t)N_NODES * D;                  // 2 x 12.8 MB ping-pong

    const int* e_src = ei;                // edge_index[0]
    const int* e_dst = ei + N_EDGES;      // edge_index[1]
    const int* x_src = eei;
    const int* x_dst = eei + N_EDGES;

    const int n4 = N_NODES * D / 4;       // 800000 float4s
    dim3 blk(256);

    auto agg = [&](const float* xin, float* xout, const int* s, const int* d) {
        copy_f4<<<(n4 + 255) / 256, blk, 0, stream>>>((const float4*)xin, (float4*)xout, n4);
        scatter_add<<<(N_EDGES * 16) / 256, blk, 0, stream>>>(xin, xout, s, d);
    };

    const float* x = x_in;
    float* buf[2] = {A, B};
    int cur = 0;
    for (int i = 0; i < NUM_LAYERS; ++i) {
        float* h = buf[cur];
        agg(x, h, e_src, e_dst);                          // h = x + scatter(x, real graph)
        float* y = buf[1 - cur];
        linear_relu<<<N_NODES / 4, blk, 0, stream>>>(h, y,
                                                     Ws + (size_t)i * D * D,
                                                     bs + (size_t)i * D);
        float* xn = buf[cur];                             // h's buffer is dead now
        agg(y, xn, x_src, x_dst);                         // x = y + scatter(y, expander)
        x = xn;
        cur = 1 - cur;
    }

    hipMemsetAsync(d_out, 0, (size_t)NUM_GRAPHS * D * sizeof(float), stream);
    pool_kernel<<<(N_NODES * 16) / 256, blk, 0, stream>>>(x, batch, out);
}

// Round 2
// 680.907 us; speedup vs baseline: 8.4879x; 8.4879x over previous
//
#include <hip/hip_runtime.h>

#define N_NODES 50000
#define N_EDGES 800000
#define D 64
#define NUM_LAYERS 4
#define NUM_GRAPHS 128
#define NB_SCAN ((N_NODES + 255) / 256)   // 196 blocks for the degree scan

// ================= CSR build =================

__global__ void hist_kernel(const int* __restrict__ dst, int* __restrict__ deg) {
    int e = blockIdx.x * blockDim.x + threadIdx.x;
    if (e < N_EDGES) atomicAdd(&deg[dst[e]], 1);
}

__global__ void scan_partial(const int* __restrict__ deg, int* __restrict__ bsum) {
    __shared__ int s[256];
    int t = threadIdx.x;
    int idx = blockIdx.x * 256 + t;
    s[t] = (idx < N_NODES) ? deg[idx] : 0;
    __syncthreads();
    for (int off = 128; off > 0; off >>= 1) {
        if (t < off) s[t] += s[t + off];
        __syncthreads();
    }
    if (t == 0) bsum[blockIdx.x] = s[0];
}

// single block, exclusive-scan nb (<=256) block sums in place
__global__ void scan_bsums(int* __restrict__ bsum, int nb) {
    __shared__ int s[256];
    int t = threadIdx.x;
    int v = (t < nb) ? bsum[t] : 0;
    s[t] = v;
    __syncthreads();
    for (int off = 1; off < 256; off <<= 1) {
        int tv = (t >= off) ? s[t - off] : 0;
        __syncthreads();
        s[t] += tv;
        __syncthreads();
    }
    if (t < nb) bsum[t] = s[t] - v;   // exclusive
}

__global__ void scan_write(const int* __restrict__ deg, const int* __restrict__ bsum,
                           int* __restrict__ rowptr, int* __restrict__ cursor) {
    __shared__ int s[256];
    int t = threadIdx.x;
    int idx = blockIdx.x * 256 + t;
    int v = (idx < N_NODES) ? deg[idx] : 0;
    s[t] = v;
    __syncthreads();
    for (int off = 1; off < 256; off <<= 1) {
        int tv = (t >= off) ? s[t - off] : 0;
        __syncthreads();
        s[t] += tv;
        __syncthreads();
    }
    if (idx < N_NODES) {
        int excl = s[t] - v + bsum[blockIdx.x];
        rowptr[idx] = excl;
        cursor[idx] = excl;
    }
    if (blockIdx.x == 0 && t == 0) rowptr[N_NODES] = N_EDGES;  // sum of degrees
}

__global__ void fill_kernel(const int* __restrict__ src, const int* __restrict__ dst,
                            int* __restrict__ cursor, int* __restrict__ col) {
    int e = blockIdx.x * blockDim.x + threadIdx.x;
    if (e < N_EDGES) {
        int p = atomicAdd(&cursor[dst[e]], 1);
        col[p] = src[e];
    }
}

// ================= gather aggregation: out[i] = x[i] + sum_{e in row i} x[col[e]] =================
// One wave per node; lane = feature. col[e] load is a wave-broadcast; x row read is 256B coalesced.
__global__ __launch_bounds__(256) void gather_add(const float* __restrict__ x,
                                                  float* __restrict__ out,
                                                  const int* __restrict__ rowptr,
                                                  const int* __restrict__ col) {
    int node = blockIdx.x * 4 + (threadIdx.x >> 6);
    int lane = threadIdx.x & 63;
    int beg = rowptr[node];
    int end = rowptr[node + 1];
    float acc = x[(size_t)node * D + lane];
    int e = beg;
    for (; e + 4 <= end; e += 4) {       // 4 outstanding row loads to hide latency
        int s0 = col[e], s1 = col[e + 1], s2 = col[e + 2], s3 = col[e + 3];
        float v0 = x[(size_t)s0 * D + lane];
        float v1 = x[(size_t)s1 * D + lane];
        float v2 = x[(size_t)s2 * D + lane];
        float v3 = x[(size_t)s3 * D + lane];
        acc += v0 + v1 + v2 + v3;
    }
    for (; e < end; ++e)
        acc += x[(size_t)col[e] * D + lane];
    out[(size_t)node * D + lane] = acc;
}

// ================= y = relu(h @ W^T + b) =================
__global__ __launch_bounds__(256) void linear_relu(const float* __restrict__ h,
                                                   float* __restrict__ y,
                                                   const float* __restrict__ W,
                                                   const float* __restrict__ b) {
    __shared__ float Wl[64 * 65];
    __shared__ float hl[4 * 64];
    int tid = threadIdx.x;
#pragma unroll
    for (int i = 0; i < 16; ++i) {
        int idx = i * 256 + tid;
        Wl[(idx >> 6) * 65 + (idx & 63)] = W[idx];
    }
    int node0 = blockIdx.x * 4;
    hl[tid] = h[(size_t)node0 * D + tid];
    __syncthreads();
    int o  = tid & 63;
    int nl = tid >> 6;
    float acc = b[o];
#pragma unroll
    for (int k = 0; k < 64; ++k)
        acc += hl[nl * 64 + k] * Wl[o * 65 + k];
    acc = fmaxf(acc, 0.0f);
    y[(size_t)(node0 + nl) * D + o] = acc;
}

// ================= pool: batch is sorted -> contiguous segments =================
__device__ __forceinline__ int lower_bound_dev(const int* __restrict__ a, int n, int v) {
    int lo = 0, hi = n;
    while (lo < hi) { int mid = (lo + hi) >> 1; if (a[mid] < v) lo = mid + 1; else hi = mid; }
    return lo;
}

__global__ __launch_bounds__(256) void pool_seg(const float* __restrict__ x,
                                                const int* __restrict__ batch,
                                                float* __restrict__ out) {
    int g = blockIdx.x;
    int lo = lower_bound_dev(batch, N_NODES, g);
    int hi = lower_bound_dev(batch, N_NODES, g + 1);
    int lane = threadIdx.x & 63;
    int sub = threadIdx.x >> 6;
    float acc = 0.0f;
    for (int n = lo + sub; n < hi; n += 4)
        acc += x[(size_t)n * D + lane];
    __shared__ float red[256];
    red[threadIdx.x] = acc;
    __syncthreads();
    if (sub == 0)
        out[(size_t)g * D + lane] = red[lane] + red[64 + lane] + red[128 + lane] + red[192 + lane];
}

// ================= host =================
extern "C" void kernel_launch(void* const* d_in, const int* in_sizes, int n_in,
                              void* d_out, int out_size, void* d_ws, size_t ws_size,
                              hipStream_t stream) {
    const float* x_in  = (const float*)d_in[0];
    const int*   ei    = (const int*)d_in[1];
    const int*   eei   = (const int*)d_in[2];
    const int*   batch = (const int*)d_in[3];
    const float* Ws    = (const float*)d_in[4];
    const float* bs    = (const float*)d_in[5];
    float* out = (float*)d_out;

    // workspace layout
    float* A = (float*)d_ws;
    float* B = A + (size_t)N_NODES * D;
    int* p = (int*)(B + (size_t)N_NODES * D);
    int* rowptrR = p;            p += N_NODES + 1;
    int* rowptrX = p;            p += N_NODES + 1;
    int* cursorR = p;            p += N_NODES;
    int* cursorX = p;            p += N_NODES;
    int* colR    = p;            p += N_EDGES;
    int* colX    = p;            p += N_EDGES;
    int* deg     = p;            p += N_NODES;   // shared tmp
    int* bsum    = p;            p += 256;       // shared tmp

    const int* e_src = ei;
    const int* e_dst = ei + N_EDGES;
    const int* x_src = eei;
    const int* x_dst = eei + N_EDGES;

    dim3 blk(256);
    int egrid = (N_EDGES + 255) / 256;

    auto build_csr = [&](const int* src, const int* dst, int* rowptr, int* cursor, int* col) {
        hipMemsetAsync(deg, 0, N_NODES * sizeof(int), stream);
        hist_kernel<<<egrid, blk, 0, stream>>>(dst, deg);
        scan_partial<<<NB_SCAN, blk, 0, stream>>>(deg, bsum);
        scan_bsums<<<1, blk, 0, stream>>>(bsum, NB_SCAN);
        scan_write<<<NB_SCAN, blk, 0, stream>>>(deg, bsum, rowptr, cursor);
        fill_kernel<<<egrid, blk, 0, stream>>>(src, dst, cursor, col);
    };

    build_csr(e_src, e_dst, rowptrR, cursorR, colR);
    build_csr(x_src, x_dst, rowptrX, cursorX, colX);

    const float* x = x_in;
    float* buf[2] = {A, B};
    int cur = 0;
    for (int i = 0; i < NUM_LAYERS; ++i) {
        float* h = buf[cur];
        gather_add<<<N_NODES / 4, blk, 0, stream>>>(x, h, rowptrR, colR);
        float* y = buf[1 - cur];
        linear_relu<<<N_NODES / 4, blk, 0, stream>>>(h, y,
                                                     Ws + (size_t)i * D * D,
                                                     bs + (size_t)i * D);
        float* xn = buf[cur];
        gather_add<<<N_NODES / 4, blk, 0, stream>>>(y, xn, rowptrX, colX);
        x = xn;
        cur = 1 - cur;
    }

    pool_seg<<<NUM_GRAPHS, blk, 0, stream>>>(x, batch, out);
}

// Round 3
// 547.750 us; speedup vs baseline: 10.5513x; 1.2431x over previous
//
#include <hip/hip_runtime.h>

#define N_NODES 50000
#define N_EDGES 800000
#define D 64
#define NUM_LAYERS 4
#define NUM_GRAPHS 128
#define NB_SCAN ((N_NODES + 255) / 256)

// ================= CSR build =================

__global__ void hist_kernel(const int* __restrict__ dst, int* __restrict__ deg) {
    int e = blockIdx.x * blockDim.x + threadIdx.x;
    if (e < N_EDGES) atomicAdd(&deg[dst[e]], 1);
}

__global__ void scan_partial(const int* __restrict__ deg, int* __restrict__ bsum) {
    __shared__ int s[256];
    int t = threadIdx.x;
    int idx = blockIdx.x * 256 + t;
    s[t] = (idx < N_NODES) ? deg[idx] : 0;
    __syncthreads();
    for (int off = 128; off > 0; off >>= 1) {
        if (t < off) s[t] += s[t + off];
        __syncthreads();
    }
    if (t == 0) bsum[blockIdx.x] = s[0];
}

__global__ void scan_bsums(int* __restrict__ bsum, int nb) {
    __shared__ int s[256];
    int t = threadIdx.x;
    int v = (t < nb) ? bsum[t] : 0;
    s[t] = v;
    __syncthreads();
    for (int off = 1; off < 256; off <<= 1) {
        int tv = (t >= off) ? s[t - off] : 0;
        __syncthreads();
        s[t] += tv;
        __syncthreads();
    }
    if (t < nb) bsum[t] = s[t] - v;
}

__global__ void scan_write(const int* __restrict__ deg, const int* __restrict__ bsum,
                           int* __restrict__ rowptr, int* __restrict__ cursor) {
    __shared__ int s[256];
    int t = threadIdx.x;
    int idx = blockIdx.x * 256 + t;
    int v = (idx < N_NODES) ? deg[idx] : 0;
    s[t] = v;
    __syncthreads();
    for (int off = 1; off < 256; off <<= 1) {
        int tv = (t >= off) ? s[t - off] : 0;
        __syncthreads();
        s[t] += tv;
        __syncthreads();
    }
    if (idx < N_NODES) {
        int excl = s[t] - v + bsum[blockIdx.x];
        rowptr[idx] = excl;
        cursor[idx] = excl;
    }
    if (blockIdx.x == 0 && t == 0) rowptr[N_NODES] = N_EDGES;
}

__global__ void fill_kernel(const int* __restrict__ src, const int* __restrict__ dst,
                            int* __restrict__ cursor, int* __restrict__ col) {
    int e = blockIdx.x * blockDim.x + threadIdx.x;
    if (e < N_EDGES) {
        int p = atomicAdd(&cursor[dst[e]], 1);
        col[p] = src[e];
    }
}

// ================= float4 gather: out[i] = x[i] + sum_{e in row i} x[col[e]] =================
// 16 lanes per node (float4/lane), 4 nodes per wave, 16 nodes per block.
__global__ __launch_bounds__(256) void gather4(const float4* __restrict__ x4,
                                               float4* __restrict__ out4,
                                               const int* __restrict__ rowptr,
                                               const int* __restrict__ col) {
    int t = threadIdx.x;
    int grp = t >> 4;                 // 0..15: node within block
    int ln  = t & 15;                 // float4 slot within row
    int node = blockIdx.x * 16 + grp;
    int beg = rowptr[node];
    int end = rowptr[node + 1];
    float4 acc = x4[(size_t)node * 16 + ln];
    int e = beg;
    for (; e + 4 <= end; e += 4) {
        int s0 = col[e], s1 = col[e + 1], s2 = col[e + 2], s3 = col[e + 3];
        float4 v0 = x4[(size_t)s0 * 16 + ln];
        float4 v1 = x4[(size_t)s1 * 16 + ln];
        float4 v2 = x4[(size_t)s2 * 16 + ln];
        float4 v3 = x4[(size_t)s3 * 16 + ln];
        acc.x += v0.x + v1.x + v2.x + v3.x;
        acc.y += v0.y + v1.y + v2.y + v3.y;
        acc.z += v0.z + v1.z + v2.z + v3.z;
        acc.w += v0.w + v1.w + v2.w + v3.w;
    }
    for (; e < end; ++e) {
        float4 v = x4[(size_t)col[e] * 16 + ln];
        acc.x += v.x; acc.y += v.y; acc.z += v.z; acc.w += v.w;
    }
    out4[(size_t)node * 16 + ln] = acc;
}

// ================= fused: y = relu( (x + gather(x)) @ W^T + b ) =================
// Same gather structure; h goes to LDS, then 64x64 GEMM from LDS.
__global__ __launch_bounds__(256) void gather4_linear(const float4* __restrict__ x4,
                                                      float* __restrict__ y,
                                                      const int* __restrict__ rowptr,
                                                      const int* __restrict__ col,
                                                      const float* __restrict__ W,
                                                      const float* __restrict__ b) {
    __shared__ float Wl[64 * 65];     // stride 65: Wl[o*65+k] read is conflict-free
    __shared__ float hl[16 * 64];     // 16 nodes x 64 feats
    int t = threadIdx.x;

#pragma unroll
    for (int i = 0; i < 16; ++i) {    // coalesced W stage
        int idx = i * 256 + t;
        Wl[(idx >> 6) * 65 + (idx & 63)] = W[idx];
    }

    int grp = t >> 4;
    int ln  = t & 15;
    int node = blockIdx.x * 16 + grp;
    int beg = rowptr[node];
    int end = rowptr[node + 1];
    float4 acc = x4[(size_t)node * 16 + ln];
    int e = beg;
    for (; e + 4 <= end; e += 4) {
        int s0 = col[e], s1 = col[e + 1], s2 = col[e + 2], s3 = col[e + 3];
        float4 v0 = x4[(size_t)s0 * 16 + ln];
        float4 v1 = x4[(size_t)s1 * 16 + ln];
        float4 v2 = x4[(size_t)s2 * 16 + ln];
        float4 v3 = x4[(size_t)s3 * 16 + ln];
        acc.x += v0.x + v1.x + v2.x + v3.x;
        acc.y += v0.y + v1.y + v2.y + v3.y;
        acc.z += v0.z + v1.z + v2.z + v3.z;
        acc.w += v0.w + v1.w + v2.w + v3.w;
    }
    for (; e < end; ++e) {
        float4 v = x4[(size_t)col[e] * 16 + ln];
        acc.x += v.x; acc.y += v.y; acc.z += v.z; acc.w += v.w;
    }
    *((float4*)(hl + grp * 64 + ln * 4)) = acc;   // b128 LDS write, 2-way (free)
    __syncthreads();

    // GEMM: 1024 outputs (16 nodes x 64), 4 per thread.
    int o  = t & 63;
    int nb = t >> 6;                  // handles nodes nb, nb+4, nb+8, nb+12
    float bo = b[o];
    float a0 = bo, a1 = bo, a2 = bo, a3 = bo;
#pragma unroll
    for (int k = 0; k < 64; ++k) {
        float w = Wl[o * 65 + k];
        a0 += hl[(nb     ) * 64 + k] * w;   // hl reads: wave-broadcast (free)
        a1 += hl[(nb +  4) * 64 + k] * w;
        a2 += hl[(nb +  8) * 64 + k] * w;
        a3 += hl[(nb + 12) * 64 + k] * w;
    }
    size_t base = (size_t)blockIdx.x * 16;
    y[(base + nb     ) * 64 + o] = fmaxf(a0, 0.0f);
    y[(base + nb +  4) * 64 + o] = fmaxf(a1, 0.0f);
    y[(base + nb +  8) * 64 + o] = fmaxf(a2, 0.0f);
    y[(base + nb + 12) * 64 + o] = fmaxf(a3, 0.0f);
}

// ================= pool: batch is sorted -> contiguous segments =================
__device__ __forceinline__ int lower_bound_dev(const int* __restrict__ a, int n, int v) {
    int lo = 0, hi = n;
    while (lo < hi) { int mid = (lo + hi) >> 1; if (a[mid] < v) lo = mid + 1; else hi = mid; }
    return lo;
}

__global__ __launch_bounds__(256) void pool_seg(const float* __restrict__ x,
                                                const int* __restrict__ batch,
                                                float* __restrict__ out) {
    int g = blockIdx.x;
    int lo = lower_bound_dev(batch, N_NODES, g);
    int hi = lower_bound_dev(batch, N_NODES, g + 1);
    int lane = threadIdx.x & 63;
    int sub = threadIdx.x >> 6;
    float acc = 0.0f;
    for (int n = lo + sub; n < hi; n += 4)
        acc += x[(size_t)n * D + lane];
    __shared__ float red[256];
    red[threadIdx.x] = acc;
    __syncthreads();
    if (sub == 0)
        out[(size_t)g * D + lane] = red[lane] + red[64 + lane] + red[128 + lane] + red[192 + lane];
}

// ================= host =================
extern "C" void kernel_launch(void* const* d_in, const int* in_sizes, int n_in,
                              void* d_out, int out_size, void* d_ws, size_t ws_size,
                              hipStream_t stream) {
    const float* x_in  = (const float*)d_in[0];
    const int*   ei    = (const int*)d_in[1];
    const int*   eei   = (const int*)d_in[2];
    const int*   batch = (const int*)d_in[3];
    const float* Ws    = (const float*)d_in[4];
    const float* bs    = (const float*)d_in[5];
    float* out = (float*)d_out;

    float* A = (float*)d_ws;                       // y buffer
    float* B = A + (size_t)N_NODES * D;            // x buffer
    int* p = (int*)(B + (size_t)N_NODES * D);
    int* rowptrR = p;            p += N_NODES + 1;
    int* rowptrX = p;            p += N_NODES + 1;
    int* cursorR = p;            p += N_NODES;
    int* cursorX = p;            p += N_NODES;
    int* colR    = p;            p += N_EDGES;
    int* colX    = p;            p += N_EDGES;
    int* deg     = p;            p += N_NODES;
    int* bsum    = p;            p += 256;

    const int* e_src = ei;
    const int* e_dst = ei + N_EDGES;
    const int* x_src = eei;
    const int* x_dst = eei + N_EDGES;

    dim3 blk(256);
    int egrid = (N_EDGES + 255) / 256;

    auto build_csr = [&](const int* src, const int* dst, int* rowptr, int* cursor, int* col) {
        hipMemsetAsync(deg, 0, N_NODES * sizeof(int), stream);
        hist_kernel<<<egrid, blk, 0, stream>>>(dst, deg);
        scan_partial<<<NB_SCAN, blk, 0, stream>>>(deg, bsum);
        scan_bsums<<<1, blk, 0, stream>>>(bsum, NB_SCAN);
        scan_write<<<NB_SCAN, blk, 0, stream>>>(deg, bsum, rowptr, cursor);
        fill_kernel<<<egrid, blk, 0, stream>>>(src, dst, cursor, col);
    };

    build_csr(e_src, e_dst, rowptrR, cursorR, colR);
    build_csr(x_src, x_dst, rowptrX, cursorX, colX);

    const int ngrid = N_NODES / 16;   // 3125 blocks
    const float* x = x_in;
    for (int i = 0; i < NUM_LAYERS; ++i) {
        // y(A) = relu( gin_agg(x, real) @ W^T + b )   [h never materialized]
        gather4_linear<<<ngrid, blk, 0, stream>>>((const float4*)x, A, rowptrR, colR,
                                                  Ws + (size_t)i * D * D,
                                                  bs + (size_t)i * D);
        // x(B) = gin_agg(y, expander)
        gather4<<<ngrid, blk, 0, stream>>>((const float4*)A, (float4*)B, rowptrX, colX);
        x = B;
    }

    pool_seg<<<NUM_GRAPHS, blk, 0, stream>>>(x, batch, out);
}